// Round 2
// baseline (332.516 us; speedup 1.0000x reference)
//
#include <hip/hip_runtime.h>

// HoloGraphBlockV7 — round 2: f32 I/O contract (inputs/outputs are float32 per
// the reference; round-1 NaN came from misreading f32 buffers as bf16).
// Internally: activations/weights cast to bf16 for MFMA GEMMs; residual stream,
// gates, and the decay recurrence stay f32.

typedef unsigned short u16;
typedef unsigned int u32;
typedef __attribute__((ext_vector_type(8))) short short8;
typedef __attribute__((ext_vector_type(4))) float floatx4;

__device__ __forceinline__ float b2f(u16 u) {
  u32 x = ((u32)u) << 16;
  return __uint_as_float(x);
}
__device__ __forceinline__ u16 f2b(float f) {
  u32 x = __float_as_uint(f);
  u32 r = (x + 0x7fffu + ((x >> 16) & 1u)) >> 16;
  return (u16)r;
}
__device__ __forceinline__ float4 b4_to_f4(uint2 u) {
  float4 r;
  r.x = __uint_as_float((u.x & 0xffffu) << 16);
  r.y = __uint_as_float(u.x & 0xffff0000u);
  r.z = __uint_as_float((u.y & 0xffffu) << 16);
  r.w = __uint_as_float(u.y & 0xffff0000u);
  return r;
}

__device__ __forceinline__ void stage16(const u16* g, u16* lds_wave_base, int lane) {
  __builtin_amdgcn_global_load_lds((const __attribute__((address_space(1))) void*)g,
                                   (__attribute__((address_space(3))) void*)lds_wave_base,
                                   16, 0, 0);
  (void)lane;
}

// ---------------------------------------------------------------------------
// Transpose + f32->bf16 convert: src f32 (R x C) -> dst bf16 (C x R)
__global__ void transpose_cvt(const float* __restrict__ src, u16* __restrict__ dst,
                              int R, int C) {
  __shared__ float tile[32][33];
  int c0 = blockIdx.x * 32, r0 = blockIdx.y * 32;
  int tx = threadIdx.x, ty = threadIdx.y;  // 32 x 8
#pragma unroll
  for (int i = 0; i < 4; ++i)
    tile[ty + i * 8][tx] = src[(size_t)(r0 + ty + i * 8) * C + c0 + tx];
  __syncthreads();
#pragma unroll
  for (int i = 0; i < 4; ++i)
    dst[(size_t)(c0 + ty + i * 8) * R + r0 + tx] = f2b(tile[tx][ty + i * 8]);
}

// Pack Wd/Wgw/Wgf (512x8 f32 each) into rows 1536..1663 of WTQ (1664x512 bf16),
// plus the fused f32 bias vector (1664).
__global__ void pack_small(const float* __restrict__ Wd, const float* __restrict__ Wgw,
                           const float* __restrict__ Wgf, const float* __restrict__ bk,
                           const float* __restrict__ bq, const float* __restrict__ bv,
                           const float* __restrict__ bd, const float* __restrict__ bgw,
                           const float* __restrict__ bgf, u16* __restrict__ WTQ,
                           float* __restrict__ biasq) {
  int idx = blockIdx.x * blockDim.x + threadIdx.x;
  int stride = gridDim.x * blockDim.x;
  for (int i = idx; i < 128 * 512; i += stride) {
    int local = i >> 9;
    int k = i & 511;
    float v = 0.f;
    if (local < 8) v = Wd[k * 8 + local];
    else if (local < 16) v = Wgw[k * 8 + (local - 8)];
    else if (local < 24) v = Wgf[k * 8 + (local - 16)];
    WTQ[(size_t)(1536 + local) * 512 + k] = f2b(v);
  }
  for (int i = idx; i < 1664; i += stride) {
    float v = 0.f;
    if (i < 512) v = bk[i];
    else if (i < 1024) v = bq[i - 512];
    else if (i < 1536) v = bv[i - 1024];
    else if (i < 1544) v = bd[i - 1536];
    else if (i < 1552) v = bgw[i - 1544];
    else if (i < 1560) v = bgf[i - 1552];
    biasq[i] = v;
  }
}

// ---------------------------------------------------------------------------
// LayerNorm over E=512, f32 in -> bf16 out. 2048 rows, 256 threads.
__global__ void ln_f32(const float* __restrict__ X, const float* __restrict__ g,
                       const float* __restrict__ bt, u16* __restrict__ Y) {
  int row = blockIdx.x, tid = threadIdx.x;
  const float* xr = X + (size_t)row * 512;
  float x0 = xr[tid], x1 = xr[tid + 256];
  float s = x0 + x1, ss = x0 * x0 + x1 * x1;
#pragma unroll
  for (int o = 32; o > 0; o >>= 1) { s += __shfl_xor(s, o); ss += __shfl_xor(ss, o); }
  __shared__ float red[8];
  if ((tid & 63) == 0) { red[tid >> 6] = s; red[4 + (tid >> 6)] = ss; }
  __syncthreads();
  float ts = red[0] + red[1] + red[2] + red[3];
  float tss = red[4] + red[5] + red[6] + red[7];
  float mu = ts * (1.f / 512.f);
  float var = tss * (1.f / 512.f) - mu * mu;
  float rstd = 1.0f / sqrtf(var + 1e-5f);
  Y[(size_t)row * 512 + tid] = f2b((x0 - mu) * rstd * g[tid] + bt[tid]);
  Y[(size_t)row * 512 + tid + 256] =
      f2b((x1 - mu) * rstd * g[tid + 256] + bt[tid + 256]);
}

// ---------------------------------------------------------------------------
// bf16 MFMA GEMM: C(MxN,f32) = A(MxK,bf16) @ BT(NxK,bf16)^T + bias(N,f32).
// 128x128 tile, BK=32, 256 threads (2x2 waves, each 64x64 via 4x4 MFMA 16x16x32).
__global__ __launch_bounds__(256, 2) void gemm_bt(const u16* __restrict__ A,
                                                  const u16* __restrict__ BT,
                                                  const float* __restrict__ bias,
                                                  float* __restrict__ C, int M, int N,
                                                  int K) {
  __shared__ __align__(16) u16 As[128 * 32];
  __shared__ __align__(16) u16 Bs[128 * 32];
  const int tid = threadIdx.x;
  const int lane = tid & 63, wave = tid >> 6;
  const int wm = wave >> 1, wn = wave & 1;
  const int m0 = blockIdx.y * 128, n0 = blockIdx.x * 128;

  floatx4 acc[4][4] = {};
  const int fr = lane & 15;  // fragment row (m or n)
  const int kq = lane >> 4;  // k quad

  for (int kb = 0; kb < K; kb += 32) {
#pragma unroll
    for (int r = 0; r < 2; ++r) {
      int slot = r * 256 + tid;
      int arow = slot >> 2, kw = slot & 3;
      stage16(A + (size_t)(m0 + arow) * K + kb + kw * 8,
              As + (size_t)(r * 256 + wave * 64) * 8, lane);
      stage16(BT + (size_t)(n0 + arow) * K + kb + kw * 8,
              Bs + (size_t)(r * 256 + wave * 64) * 8, lane);
    }
    asm volatile("s_waitcnt vmcnt(0)" ::: "memory");
    __syncthreads();

    short8 af[4], bf[4];
#pragma unroll
    for (int mt = 0; mt < 4; ++mt)
      af[mt] = *(const short8*)&As[(wm * 64 + mt * 16 + fr) * 32 + kq * 8];
#pragma unroll
    for (int nt = 0; nt < 4; ++nt)
      bf[nt] = *(const short8*)&Bs[(wn * 64 + nt * 16 + fr) * 32 + kq * 8];
#pragma unroll
    for (int mt = 0; mt < 4; ++mt)
#pragma unroll
      for (int nt = 0; nt < 4; ++nt)
        acc[mt][nt] =
            __builtin_amdgcn_mfma_f32_16x16x32_bf16(af[mt], bf[nt], acc[mt][nt], 0, 0, 0);
    __syncthreads();
  }

  const int col = lane & 15;
  const int rbase = (lane >> 4) * 4;
#pragma unroll
  for (int nt = 0; nt < 4; ++nt) {
    int gc = n0 + wn * 64 + nt * 16 + col;
    float bvv = bias[gc];
#pragma unroll
    for (int mt = 0; mt < 4; ++mt) {
      int gr = m0 + wm * 64 + mt * 16 + rbase;
#pragma unroll
      for (int r = 0; r < 4; ++r)
        C[(size_t)(gr + r) * N + gc] = acc[mt][nt][r] + bvv;
    }
  }
}

// ---------------------------------------------------------------------------
// Per-token epilogue of the QKV+gates GEMM. grid=2048 tokens, block=512.
__global__ __launch_bounds__(512) void post_qkvg(const float* __restrict__ C0,
                                                 u16* __restrict__ KB, u16* __restrict__ QB,
                                                 u16* __restrict__ VG,
                                                 float* __restrict__ DEC) {
  int tok = blockIdx.x;
  int b = tok >> 10, t = tok & 1023;
  int tid = threadIdx.x;
  int h = tid >> 6, d = tid & 63;
  const float* row = C0 + (size_t)tok * 1664;

  float dl = row[1536 + h], gwl = row[1544 + h], gfl = row[1552 + h];
  float dd = dl > 20.f ? dl : log1pf(expf(dl));
  float sw = 1.f / (1.f + expf(-gwl));
  float gw = sw * sw;
  float sf = 1.f / (1.f + expf(-gfl));
  float gf = 1.f - sf * sf;

  size_t obase = ((size_t)(b * 8 + h) * 1024 + t) * 64 + d;

  float kx = row[h * 64 + d];
  float ssk = kx * kx;
#pragma unroll
  for (int o = 32; o > 0; o >>= 1) ssk += __shfl_xor(ssk, o);
  KB[obase] = f2b(kx / fmaxf(sqrtf(ssk), 1e-12f));

  float qx = row[512 + h * 64 + d];
  float ssq = qx * qx;
#pragma unroll
  for (int o = 32; o > 0; o >>= 1) ssq += __shfl_xor(ssq, o);
  QB[obase] = f2b(qx / fmaxf(sqrtf(ssq), 1e-12f));

  float vx = tanhf(row[1024 + h * 64 + d]);
  VG[obase] = f2b(vx * (dd * gw));

  if (d == 0)
    DEC[(size_t)(b * 8 + h) * 1024 + t] = fminf(fmaxf(dd * gf, 1e-6f), 0.999f);
}

// Cumulative log-decay per (b,h); update weight w_t = c/(c+1e-8), c = exp(Lcum).
__global__ void logcum(const float* __restrict__ DEC, float* __restrict__ LC,
                       float* __restrict__ WW) {
  int bh = blockIdx.x;
  int lane = threadIdx.x;  // 64
  size_t base = (size_t)bh * 1024 + lane * 16;
  float loc[16];
  float run = 0.f;
#pragma unroll
  for (int i = 0; i < 16; ++i) { run += logf(DEC[base + i]); loc[i] = run; }
  float x = run;
#pragma unroll
  for (int o = 1; o < 64; o <<= 1) {
    float v = __shfl_up(x, o);
    if (lane >= o) x += v;
  }
  float excl = x - run;
#pragma unroll
  for (int i = 0; i < 16; ++i) {
    float L = excl + loc[i];
    LC[base + i] = L;
    float c = expf(L);
    WW[base + i] = c / (c + 1e-8f);
  }
}

// ---------------------------------------------------------------------------
// Scan phase 1: per (chunk,h,b) local scan of 64 steps with zero init.
__global__ __launch_bounds__(256, 2) void scan_phase1(
    const u16* __restrict__ KB, const u16* __restrict__ QB, const u16* __restrict__ VG,
    const float* __restrict__ DEC, const float* __restrict__ WW,
    float* __restrict__ RP, float* __restrict__ SF) {
  int chunk = blockIdx.x, h = blockIdx.y, b = blockIdx.z;
  int bh = b * 8 + h;
  int t0 = chunk * 64;
  __shared__ __align__(16) float sk[4096], sq[4096], sv[4096];
  __shared__ float lsa[64], lsw[64];
  int tid = threadIdx.x, lane = tid & 63, wave = tid >> 6;

  const u16* gk = KB + ((size_t)bh * 1024 + t0) * 64;
  const u16* gq = QB + ((size_t)bh * 1024 + t0) * 64;
  const u16* gv = VG + ((size_t)bh * 1024 + t0) * 64;
#pragma unroll
  for (int r = 0; r < 4; ++r) {
    int f = ((wave * 4 + r) * 64 + lane) * 4;
    *(float4*)&sk[f] = b4_to_f4(*(const uint2*)(gk + f));
    *(float4*)&sq[f] = b4_to_f4(*(const uint2*)(gq + f));
    *(float4*)&sv[f] = b4_to_f4(*(const uint2*)(gv + f));
  }
  if (tid < 64) {
    lsa[tid] = DEC[(size_t)bh * 1024 + t0 + tid];
    lsw[tid] = WW[(size_t)bh * 1024 + t0 + tid];
  }
  __syncthreads();

  int i = tid >> 2, j0 = (tid & 3) * 16;
  float s[16];
#pragma unroll
  for (int z = 0; z < 16; ++z) s[z] = 0.f;

  for (int t = 0; t < 64; ++t) {
    float a = lsa[t], w = lsw[t];
    float wv = w * sv[t * 64 + i];
    float r = 0.f;
#pragma unroll
    for (int u4 = 0; u4 < 4; ++u4) {
      float4 kv = *(const float4*)&sk[t * 64 + j0 + u4 * 4];
      float4 qv = *(const float4*)&sq[t * 64 + j0 + u4 * 4];
      s[u4 * 4 + 0] = fmaf(a, s[u4 * 4 + 0], wv * kv.x); r = fmaf(s[u4 * 4 + 0], qv.x, r);
      s[u4 * 4 + 1] = fmaf(a, s[u4 * 4 + 1], wv * kv.y); r = fmaf(s[u4 * 4 + 1], qv.y, r);
      s[u4 * 4 + 2] = fmaf(a, s[u4 * 4 + 2], wv * kv.z); r = fmaf(s[u4 * 4 + 2], qv.z, r);
      s[u4 * 4 + 3] = fmaf(a, s[u4 * 4 + 3], wv * kv.w); r = fmaf(s[u4 * 4 + 3], qv.w, r);
    }
    r += __shfl_xor(r, 1);
    r += __shfl_xor(r, 2);
    if ((tid & 3) == 0)
      RP[((size_t)(b * 1024 + t0 + t) * 8 + h) * 64 + i] = r;
  }

  float* Sf = SF + ((size_t)bh * 16 + chunk) * 4096 + i * 64 + j0;
#pragma unroll
  for (int u4 = 0; u4 < 4; ++u4) {
    float4 v;
    v.x = s[u4 * 4 + 0]; v.y = s[u4 * 4 + 1]; v.z = s[u4 * 4 + 2]; v.w = s[u4 * 4 + 3];
    *(float4*)&Sf[u4 * 4] = v;
  }
}

// Scan phase 2: sequential cross-chunk combine (16 chunks). grid = 16 (b,h).
// Also emits next_mem (f32).
__global__ void scan_phase2(const float* __restrict__ SF, const float* __restrict__ LC,
                            float* __restrict__ SI, float* __restrict__ next_mem) {
  int bh = blockIdx.x;
  int tid = threadIdx.x;  // 256
  float s[16];
#pragma unroll
  for (int z = 0; z < 16; ++z) s[z] = 0.f;
  for (int c = 0; c < 16; ++c) {
#pragma unroll
    for (int z = 0; z < 16; ++z)
      SI[((size_t)bh * 16 + c) * 4096 + z * 256 + tid] = s[z];
    float Lend = LC[(size_t)bh * 1024 + c * 64 + 63];
    float Lpre = c ? LC[(size_t)bh * 1024 + c * 64 - 1] : 0.f;
    float P = expf(Lend - Lpre);
#pragma unroll
    for (int z = 0; z < 16; ++z)
      s[z] = fmaf(P, s[z], SF[((size_t)bh * 16 + c) * 4096 + z * 256 + tid]);
  }
#pragma unroll
  for (int z = 0; z < 16; ++z)
    next_mem[(size_t)bh * 4096 + z * 256 + tid] = s[z];
}

// Scan phase 3: add inter-chunk contribution p_t*(Sinit @ q_t); write bf16 readout.
__global__ __launch_bounds__(256, 2) void scan_phase3(
    const u16* __restrict__ QB, const float* __restrict__ SI, const float* __restrict__ LC,
    const float* __restrict__ RP, u16* __restrict__ AB) {
  int chunk = blockIdx.x, h = blockIdx.y, b = blockIdx.z;
  int bh = b * 8 + h;
  int t0 = chunk * 64;
  __shared__ __align__(16) float sq[4096];
  __shared__ float sL[64];
  int tid = threadIdx.x, lane = tid & 63, wave = tid >> 6;

  const u16* gq = QB + ((size_t)bh * 1024 + t0) * 64;
#pragma unroll
  for (int r = 0; r < 4; ++r) {
    int f = ((wave * 4 + r) * 64 + lane) * 4;
    *(float4*)&sq[f] = b4_to_f4(*(const uint2*)(gq + f));
  }
  if (tid < 64) sL[tid] = LC[(size_t)bh * 1024 + t0 + tid];
  __syncthreads();

  float Lpre = chunk ? LC[(size_t)bh * 1024 + t0 - 1] : 0.f;
  int i = tid >> 2, j0 = (tid & 3) * 16;
  const float* Si = SI + ((size_t)bh * 16 + chunk) * 4096 + i * 64 + j0;
  float S[16];
#pragma unroll
  for (int u4 = 0; u4 < 4; ++u4) {
    float4 v = *(const float4*)&Si[u4 * 4];
    S[u4 * 4 + 0] = v.x; S[u4 * 4 + 1] = v.y; S[u4 * 4 + 2] = v.z; S[u4 * 4 + 3] = v.w;
  }

  for (int t = 0; t < 64; ++t) {
    float p = expf(sL[t] - Lpre);
    float r = 0.f;
#pragma unroll
    for (int u4 = 0; u4 < 4; ++u4) {
      float4 qv = *(const float4*)&sq[t * 64 + j0 + u4 * 4];
      r = fmaf(S[u4 * 4 + 0], qv.x, r);
      r = fmaf(S[u4 * 4 + 1], qv.y, r);
      r = fmaf(S[u4 * 4 + 2], qv.z, r);
      r = fmaf(S[u4 * 4 + 3], qv.w, r);
    }
    r += __shfl_xor(r, 1);
    r += __shfl_xor(r, 2);
    if ((tid & 3) == 0) {
      size_t gi = ((size_t)(b * 1024 + t0 + t) * 8 + h) * 64 + i;
      AB[gi] = f2b(RP[gi] + p * r);
    }
  }
}

// ---------------------------------------------------------------------------
// Elementwise glue (f32 residual stream).
__global__ void x2_kernel(const float* __restrict__ x, const float* __restrict__ Co,
                          const float* __restrict__ motif, float* __restrict__ X2, int n) {
  int idx = blockIdx.x * blockDim.x + threadIdx.x;
  if (idx < n) X2[idx] = x[idx] + Co[idx] + 0.1f * motif[idx];
}

__global__ void gelu_kernel(const float* __restrict__ C1, u16* __restrict__ MID, int n) {
  int idx = blockIdx.x * blockDim.x + threadIdx.x;
  if (idx < n) {
    float v = C1[idx];
    MID[idx] = f2b(0.5f * v * (1.f + erff(v * 0.70710678118654752f)));
  }
}

__global__ void x3_kernel(const float* __restrict__ X2, const float* __restrict__ C2,
                          float* __restrict__ out0, u16* __restrict__ X3B, int n) {
  int idx = blockIdx.x * blockDim.x + threadIdx.x;
  if (idx < n) {
    float v = X2[idx] + C2[idx];
    out0[idx] = v;
    X3B[idx] = f2b(v);
  }
}

__global__ void outs_kernel(const float* __restrict__ bmin, const float* __restrict__ bmax,
                            const float* __restrict__ Cp, float* __restrict__ out2,
                            float* __restrict__ out3, int n) {
  int idx = blockIdx.x * blockDim.x + threadIdx.x;
  if (idx < n) {
    float p = Cp[idx];
    out2[idx] = bmin[idx] + p;
    out3[idx] = bmax[idx] + p;
  }
}

// ---------------------------------------------------------------------------
extern "C" void kernel_launch(void* const* d_in, const int* in_sizes, int n_in,
                              void* d_out, int out_size, void* d_ws, size_t ws_size,
                              hipStream_t stream) {
  const float* x = (const float*)d_in[0];
  const float* bmin = (const float*)d_in[1];
  const float* bmax = (const float*)d_in[2];
  const float* motif = (const float*)d_in[3];
  const float* Wk = (const float*)d_in[4];
  const float* bk = (const float*)d_in[5];
  const float* Wq = (const float*)d_in[6];
  const float* bq = (const float*)d_in[7];
  const float* Wv = (const float*)d_in[8];
  const float* bv = (const float*)d_in[9];
  const float* Wo = (const float*)d_in[10];
  const float* bo = (const float*)d_in[11];
  const float* Wd = (const float*)d_in[12];
  const float* bd = (const float*)d_in[13];
  const float* Wgw = (const float*)d_in[14];
  const float* bgw = (const float*)d_in[15];
  const float* Wgf = (const float*)d_in[16];
  const float* bgf = (const float*)d_in[17];
  const float* Wps = (const float*)d_in[18];
  const float* bps = (const float*)d_in[19];
  const float* ln1g = (const float*)d_in[20];
  const float* ln1b = (const float*)d_in[21];
  const float* ln2g = (const float*)d_in[22];
  const float* ln2b = (const float*)d_in[23];
  const float* W1 = (const float*)d_in[24];
  const float* b1 = (const float*)d_in[25];
  const float* W2 = (const float*)d_in[26];
  const float* b2 = (const float*)d_in[27];

  char* ws = (char*)d_ws;
  // persistent regions (bf16 weights + f32 fused bias)
  u16* WTQ = (u16*)(ws + 0);             // 1664x512
  u16* WTO = (u16*)(ws + 1703936);       // 512x512
  u16* WT1 = (u16*)(ws + 2228224);       // 2048x512
  u16* WT2 = (u16*)(ws + 4325376);       // 512x2048
  u16* WTPS = (u16*)(ws + 6422528);      // 512x512
  float* BQV = (float*)(ws + 6946816);   // f32 bias 1664 -> ends 6953472
  // arena (time-aliased)
  u16* XN = (u16*)(ws + 6953984);        // 2048x512 bf16 -> 9051136
  float* C0 = (float*)(ws + 9051136);    // 2048x1664 f32 -> 22682624
  float* C1 = (float*)(ws + 9051136);    // 2048x2048 f32 -> 25828352
  u16* KB = (u16*)(ws + 25828352);       // [b][h][t][d] bf16 -> 27925504
  u16* QB = (u16*)(ws + 27925504);       // -> 30022656
  u16* VG = (u16*)(ws + 30022656);       // -> 32119808
  float* DEC = (float*)(ws + 32119808);  // -> 32185344
  float* LC = (float*)(ws + 32185344);   // -> 32250880
  float* WW = (float*)(ws + 32250880);   // -> 32316416
  float* RP = (float*)(ws + 32316416);   // f32 [b][t][h][d] -> 36510720
  float* SF = (float*)(ws + 36510720);   // -> 40705024
  float* SI = (float*)(ws + 40705024);   // -> 44899328
  u16* AB = (u16*)(ws + 25828352);       // readout bf16 (aliases KB; KB dead)
  float* CO = (float*)(ws + 36510720);   // Wo out (aliases SF; SF dead)
  float* X2 = (float*)(ws + 40705024);   // residual f32 (aliases SI; SI dead)
  u16* HB = (u16*)(ws + 27925504);       // ln2 out (aliases QB; QB dead)
  u16* MID = (u16*)(ws + 25828352);      // 2048x2048 bf16 -> 34216960 (KB..RP dead)
  float* C2 = (float*)(ws + 36510720);   // FFN2 out (aliases CO; CO dead)
  u16* X3B = (u16*)(ws + 25828352);      // x3 bf16 (aliases MID; MID dead)
  float* CP = (float*)(ws + 27925504);   // probe out -> 32119808 (disjoint from X3B)

  float* out0 = (float*)d_out;
  float* out1 = out0 + 1048576;
  float* out2 = out0 + 1114112;
  float* out3 = out0 + 2162688;

  dim3 tb(32, 8);
  transpose_cvt<<<dim3(16, 16), tb, 0, stream>>>(Wk, WTQ, 512, 512);
  transpose_cvt<<<dim3(16, 16), tb, 0, stream>>>(Wq, WTQ + 512 * 512, 512, 512);
  transpose_cvt<<<dim3(16, 16), tb, 0, stream>>>(Wv, WTQ + 1024 * 512, 512, 512);
  transpose_cvt<<<dim3(16, 16), tb, 0, stream>>>(Wo, WTO, 512, 512);
  transpose_cvt<<<dim3(64, 16), tb, 0, stream>>>(W1, WT1, 512, 2048);
  transpose_cvt<<<dim3(16, 64), tb, 0, stream>>>(W2, WT2, 2048, 512);
  transpose_cvt<<<dim3(16, 16), tb, 0, stream>>>(Wps, WTPS, 512, 512);
  pack_small<<<64, 256, 0, stream>>>(Wd, Wgw, Wgf, bk, bq, bv, bd, bgw, bgf, WTQ, BQV);

  ln_f32<<<2048, 256, 0, stream>>>(x, ln1g, ln1b, XN);
  gemm_bt<<<dim3(13, 16), 256, 0, stream>>>(XN, WTQ, BQV, C0, 2048, 1664, 512);
  post_qkvg<<<2048, 512, 0, stream>>>(C0, KB, QB, VG, DEC);
  logcum<<<16, 64, 0, stream>>>(DEC, LC, WW);
  scan_phase1<<<dim3(16, 8, 2), 256, 0, stream>>>(KB, QB, VG, DEC, WW, RP, SF);
  scan_phase2<<<16, 256, 0, stream>>>(SF, LC, SI, out1);
  scan_phase3<<<dim3(16, 8, 2), 256, 0, stream>>>(QB, SI, LC, RP, AB);

  gemm_bt<<<dim3(4, 16), 256, 0, stream>>>(AB, WTO, bo, CO, 2048, 512, 512);
  x2_kernel<<<4096, 256, 0, stream>>>(x, CO, motif, X2, 1048576);
  ln_f32<<<2048, 256, 0, stream>>>(X2, ln2g, ln2b, HB);
  gemm_bt<<<dim3(16, 16), 256, 0, stream>>>(HB, WT1, b1, C1, 2048, 2048, 512);
  gelu_kernel<<<16384, 256, 0, stream>>>(C1, MID, 4194304);
  gemm_bt<<<dim3(4, 16), 256, 0, stream>>>(MID, WT2, b2, C2, 2048, 512, 2048);
  x3_kernel<<<4096, 256, 0, stream>>>(X2, C2, out0, X3B, 1048576);
  gemm_bt<<<dim3(4, 16), 256, 0, stream>>>(X3B, WTPS, bps, CP, 2048, 512, 512);
  outs_kernel<<<4096, 256, 0, stream>>>(bmin, bmax, CP, out2, out3, 1048576);
}

// Round 3
// 319.549 us; speedup vs baseline: 1.0406x; 1.0406x over previous
//
#include <hip/hip_runtime.h>

// HoloGraphBlockV7 — round 3: launch-count + traffic fusion.
// prep_weights (1 kernel for all transposes+pack); GEMM epilogues fused
// (x2-residual, gelu, x3, probe-outputs). 25 -> 13 dispatches.

typedef unsigned short u16;
typedef unsigned int u32;
typedef __attribute__((ext_vector_type(8))) short short8;
typedef __attribute__((ext_vector_type(4))) float floatx4;

__device__ __forceinline__ float b2f(u16 u) {
  u32 x = ((u32)u) << 16;
  return __uint_as_float(x);
}
__device__ __forceinline__ u16 f2b(float f) {
  u32 x = __float_as_uint(f);
  u32 r = (x + 0x7fffu + ((x >> 16) & 1u)) >> 16;
  return (u16)r;
}
__device__ __forceinline__ float4 b4_to_f4(uint2 u) {
  float4 r;
  r.x = __uint_as_float((u.x & 0xffffu) << 16);
  r.y = __uint_as_float(u.x & 0xffff0000u);
  r.z = __uint_as_float((u.y & 0xffffu) << 16);
  r.w = __uint_as_float(u.y & 0xffff0000u);
  return r;
}

__device__ __forceinline__ void stage16(const u16* g, u16* lds_wave_base) {
  __builtin_amdgcn_global_load_lds((const __attribute__((address_space(1))) void*)g,
                                   (__attribute__((address_space(3))) void*)lds_wave_base,
                                   16, 0, 0);
}

// ---------------------------------------------------------------------------
// All weight prep in one kernel. Blocks 0..3327: 32x32 transpose tiles
// (f32 -> bf16, dst = src^T). Blocks 3328..3391: pack gate weights + fused bias.
__global__ __launch_bounds__(256) void prep_weights(
    const float* __restrict__ Wk, const float* __restrict__ Wq,
    const float* __restrict__ Wv, const float* __restrict__ Wo,
    const float* __restrict__ Wps, const float* __restrict__ W1,
    const float* __restrict__ W2, const float* __restrict__ Wd,
    const float* __restrict__ Wgw, const float* __restrict__ Wgf,
    const float* __restrict__ bk, const float* __restrict__ bq,
    const float* __restrict__ bv, const float* __restrict__ bd,
    const float* __restrict__ bgw, const float* __restrict__ bgf,
    u16* __restrict__ WTQ, u16* __restrict__ WTO, u16* __restrict__ WTPS,
    u16* __restrict__ WT1, u16* __restrict__ WT2, float* __restrict__ BQV) {
  int bid = blockIdx.x, tid = threadIdx.x;
  if (bid < 3328) {
    const float* src;
    u16* dst;
    int C, rel, tiles_x;
    if (bid < 256)       { src = Wk;  dst = WTQ;           C = 512;  rel = bid;        tiles_x = 16; }
    else if (bid < 512)  { src = Wq;  dst = WTQ + 262144;  C = 512;  rel = bid - 256;  tiles_x = 16; }
    else if (bid < 768)  { src = Wv;  dst = WTQ + 524288;  C = 512;  rel = bid - 512;  tiles_x = 16; }
    else if (bid < 1024) { src = Wo;  dst = WTO;           C = 512;  rel = bid - 768;  tiles_x = 16; }
    else if (bid < 1280) { src = Wps; dst = WTPS;          C = 512;  rel = bid - 1024; tiles_x = 16; }
    else if (bid < 2304) { src = W1;  dst = WT1;           C = 2048; rel = bid - 1280; tiles_x = 64; }
    else                 { src = W2;  dst = WT2;           C = 512;  rel = bid - 2304; tiles_x = 16; }
    int R = (bid >= 1280 && bid < 2304) ? 512 : (bid >= 2304 ? 2048 : 512);
    int c0 = (rel % tiles_x) * 32, r0 = (rel / tiles_x) * 32;
    __shared__ float tile[32][33];
    int tx = tid & 31, ty = tid >> 5;
#pragma unroll
    for (int i = 0; i < 4; ++i)
      tile[ty + i * 8][tx] = src[(size_t)(r0 + ty + i * 8) * C + c0 + tx];
    __syncthreads();
#pragma unroll
    for (int i = 0; i < 4; ++i)
      dst[(size_t)(c0 + ty + i * 8) * R + r0 + tx] = f2b(tile[tx][ty + i * 8]);
  } else {
    int idx = (bid - 3328) * 256 + tid;
    const int stride = 64 * 256;
    for (int i = idx; i < 128 * 512; i += stride) {
      int local = i >> 9, k = i & 511;
      float v = 0.f;
      if (local < 8) v = Wd[k * 8 + local];
      else if (local < 16) v = Wgw[k * 8 + (local - 8)];
      else if (local < 24) v = Wgf[k * 8 + (local - 16)];
      WTQ[(size_t)(1536 + local) * 512 + k] = f2b(v);
    }
    for (int i = idx; i < 1664; i += stride) {
      float v = 0.f;
      if (i < 512) v = bk[i];
      else if (i < 1024) v = bq[i - 512];
      else if (i < 1536) v = bv[i - 1024];
      else if (i < 1544) v = bd[i - 1536];
      else if (i < 1552) v = bgw[i - 1544];
      else if (i < 1560) v = bgf[i - 1552];
      BQV[i] = v;
    }
  }
}

// ---------------------------------------------------------------------------
// LayerNorm over E=512, f32 in -> bf16 out.
__global__ void ln_f32(const float* __restrict__ X, const float* __restrict__ g,
                       const float* __restrict__ bt, u16* __restrict__ Y) {
  int row = blockIdx.x, tid = threadIdx.x;
  const float* xr = X + (size_t)row * 512;
  float x0 = xr[tid], x1 = xr[tid + 256];
  float s = x0 + x1, ss = x0 * x0 + x1 * x1;
#pragma unroll
  for (int o = 32; o > 0; o >>= 1) { s += __shfl_xor(s, o); ss += __shfl_xor(ss, o); }
  __shared__ float red[8];
  if ((tid & 63) == 0) { red[tid >> 6] = s; red[4 + (tid >> 6)] = ss; }
  __syncthreads();
  float ts = red[0] + red[1] + red[2] + red[3];
  float tss = red[4] + red[5] + red[6] + red[7];
  float mu = ts * (1.f / 512.f);
  float var = tss * (1.f / 512.f) - mu * mu;
  float rstd = 1.0f / sqrtf(var + 1e-5f);
  Y[(size_t)row * 512 + tid] = f2b((x0 - mu) * rstd * g[tid] + bt[tid]);
  Y[(size_t)row * 512 + tid + 256] =
      f2b((x1 - mu) * rstd * g[tid + 256] + bt[tid + 256]);
}

// ---------------------------------------------------------------------------
// bf16 MFMA GEMM with fused epilogues.
// EPI 0: outf = acc+bias
// EPI 1: outf = aux0 + (acc+bias) + 0.1*aux1          (x2 residual)
// EPI 2: outb = bf16(gelu(acc+bias))                  (FFN1 -> MID)
// EPI 3: w = aux0 + acc+bias; outf = w; outb = bf16(w) (FFN2 -> x3)
// EPI 4: p = acc+bias; outf = aux0+p; outf2 = aux1+p  (probe -> out2/out3)
template <int EPI>
__global__ __launch_bounds__(256, 2) void gemm_epi(
    const u16* __restrict__ A, const u16* __restrict__ BT, const float* __restrict__ bias,
    float* __restrict__ outf, float* __restrict__ outf2, u16* __restrict__ outb,
    const float* __restrict__ aux0, const float* __restrict__ aux1, int M, int N, int K) {
  __shared__ __align__(16) u16 As[128 * 32];
  __shared__ __align__(16) u16 Bs[128 * 32];
  const int tid = threadIdx.x;
  const int lane = tid & 63, wave = tid >> 6;
  const int wm = wave >> 1, wn = wave & 1;
  const int m0 = blockIdx.y * 128, n0 = blockIdx.x * 128;

  floatx4 acc[4][4] = {};
  const int fr = lane & 15;
  const int kq = lane >> 4;

  for (int kb = 0; kb < K; kb += 32) {
#pragma unroll
    for (int r = 0; r < 2; ++r) {
      int slot = r * 256 + tid;
      int arow = slot >> 2, kw = slot & 3;
      stage16(A + (size_t)(m0 + arow) * K + kb + kw * 8, As + (size_t)(r * 256 + wave * 64) * 8);
      stage16(BT + (size_t)(n0 + arow) * K + kb + kw * 8, Bs + (size_t)(r * 256 + wave * 64) * 8);
    }
    asm volatile("s_waitcnt vmcnt(0)" ::: "memory");
    __syncthreads();

    short8 af[4], bf[4];
#pragma unroll
    for (int mt = 0; mt < 4; ++mt)
      af[mt] = *(const short8*)&As[(wm * 64 + mt * 16 + fr) * 32 + kq * 8];
#pragma unroll
    for (int nt = 0; nt < 4; ++nt)
      bf[nt] = *(const short8*)&Bs[(wn * 64 + nt * 16 + fr) * 32 + kq * 8];
#pragma unroll
    for (int mt = 0; mt < 4; ++mt)
#pragma unroll
      for (int nt = 0; nt < 4; ++nt)
        acc[mt][nt] =
            __builtin_amdgcn_mfma_f32_16x16x32_bf16(af[mt], bf[nt], acc[mt][nt], 0, 0, 0);
    __syncthreads();
  }

  const int col = lane & 15;
  const int rbase = (lane >> 4) * 4;
#pragma unroll
  for (int nt = 0; nt < 4; ++nt) {
    int gc = n0 + wn * 64 + nt * 16 + col;
    float bvv = bias[gc];
#pragma unroll
    for (int mt = 0; mt < 4; ++mt) {
      int gr = m0 + wm * 64 + mt * 16 + rbase;
#pragma unroll
      for (int r = 0; r < 4; ++r) {
        size_t idx = (size_t)(gr + r) * N + gc;
        float v = acc[mt][nt][r] + bvv;
        if constexpr (EPI == 0) {
          outf[idx] = v;
        } else if constexpr (EPI == 1) {
          outf[idx] = aux0[idx] + v + 0.1f * aux1[idx];
        } else if constexpr (EPI == 2) {
          outb[idx] = f2b(0.5f * v * (1.f + erff(v * 0.70710678118654752f)));
        } else if constexpr (EPI == 3) {
          float w = aux0[idx] + v;
          outf[idx] = w;
          outb[idx] = f2b(w);
        } else {
          outf[idx] = aux0[idx] + v;
          outf2[idx] = aux1[idx] + v;
        }
      }
    }
  }
}

// ---------------------------------------------------------------------------
// Per-token epilogue of the QKV+gates GEMM.
__global__ __launch_bounds__(512) void post_qkvg(const float* __restrict__ C0,
                                                 u16* __restrict__ KB, u16* __restrict__ QB,
                                                 u16* __restrict__ VG,
                                                 float* __restrict__ DEC) {
  int tok = blockIdx.x;
  int b = tok >> 10, t = tok & 1023;
  int tid = threadIdx.x;
  int h = tid >> 6, d = tid & 63;
  const float* row = C0 + (size_t)tok * 1664;

  float dl = row[1536 + h], gwl = row[1544 + h], gfl = row[1552 + h];
  float dd = dl > 20.f ? dl : log1pf(expf(dl));
  float sw = 1.f / (1.f + expf(-gwl));
  float gw = sw * sw;
  float sf = 1.f / (1.f + expf(-gfl));
  float gf = 1.f - sf * sf;

  size_t obase = ((size_t)(b * 8 + h) * 1024 + t) * 64 + d;

  float kx = row[h * 64 + d];
  float ssk = kx * kx;
#pragma unroll
  for (int o = 32; o > 0; o >>= 1) ssk += __shfl_xor(ssk, o);
  KB[obase] = f2b(kx / fmaxf(sqrtf(ssk), 1e-12f));

  float qx = row[512 + h * 64 + d];
  float ssq = qx * qx;
#pragma unroll
  for (int o = 32; o > 0; o >>= 1) ssq += __shfl_xor(ssq, o);
  QB[obase] = f2b(qx / fmaxf(sqrtf(ssq), 1e-12f));

  float vx = tanhf(row[1024 + h * 64 + d]);
  VG[obase] = f2b(vx * (dd * gw));

  if (d == 0)
    DEC[(size_t)(b * 8 + h) * 1024 + t] = fminf(fmaxf(dd * gf, 1e-6f), 0.999f);
}

// Cumulative log-decay per (b,h); update weight w_t = c/(c+1e-8), c = exp(Lcum).
__global__ void logcum(const float* __restrict__ DEC, float* __restrict__ LC,
                       float* __restrict__ WW) {
  int bh = blockIdx.x;
  int lane = threadIdx.x;  // 64
  size_t base = (size_t)bh * 1024 + lane * 16;
  float loc[16];
  float run = 0.f;
#pragma unroll
  for (int i = 0; i < 16; ++i) { run += logf(DEC[base + i]); loc[i] = run; }
  float x = run;
#pragma unroll
  for (int o = 1; o < 64; o <<= 1) {
    float v = __shfl_up(x, o);
    if (lane >= o) x += v;
  }
  float excl = x - run;
#pragma unroll
  for (int i = 0; i < 16; ++i) {
    float L = excl + loc[i];
    LC[base + i] = L;
    float c = expf(L);
    WW[base + i] = c / (c + 1e-8f);
  }
}

// ---------------------------------------------------------------------------
// Scan phase 1: per (chunk,h,b) local scan of 64 steps with zero init.
__global__ __launch_bounds__(256, 2) void scan_phase1(
    const u16* __restrict__ KB, const u16* __restrict__ QB, const u16* __restrict__ VG,
    const float* __restrict__ DEC, const float* __restrict__ WW,
    float* __restrict__ RP, float* __restrict__ SF) {
  int chunk = blockIdx.x, h = blockIdx.y, b = blockIdx.z;
  int bh = b * 8 + h;
  int t0 = chunk * 64;
  __shared__ __align__(16) float sk[4096], sq[4096], sv[4096];
  __shared__ float lsa[64], lsw[64];
  int tid = threadIdx.x, lane = tid & 63, wave = tid >> 6;

  const u16* gk = KB + ((size_t)bh * 1024 + t0) * 64;
  const u16* gq = QB + ((size_t)bh * 1024 + t0) * 64;
  const u16* gv = VG + ((size_t)bh * 1024 + t0) * 64;
#pragma unroll
  for (int r = 0; r < 4; ++r) {
    int f = ((wave * 4 + r) * 64 + lane) * 4;
    *(float4*)&sk[f] = b4_to_f4(*(const uint2*)(gk + f));
    *(float4*)&sq[f] = b4_to_f4(*(const uint2*)(gq + f));
    *(float4*)&sv[f] = b4_to_f4(*(const uint2*)(gv + f));
  }
  if (tid < 64) {
    lsa[tid] = DEC[(size_t)bh * 1024 + t0 + tid];
    lsw[tid] = WW[(size_t)bh * 1024 + t0 + tid];
  }
  __syncthreads();

  int i = tid >> 2, j0 = (tid & 3) * 16;
  float s[16];
#pragma unroll
  for (int z = 0; z < 16; ++z) s[z] = 0.f;

  for (int t = 0; t < 64; ++t) {
    float a = lsa[t], w = lsw[t];
    float wv = w * sv[t * 64 + i];
    float r = 0.f;
#pragma unroll
    for (int u4 = 0; u4 < 4; ++u4) {
      float4 kv = *(const float4*)&sk[t * 64 + j0 + u4 * 4];
      float4 qv = *(const float4*)&sq[t * 64 + j0 + u4 * 4];
      s[u4 * 4 + 0] = fmaf(a, s[u4 * 4 + 0], wv * kv.x); r = fmaf(s[u4 * 4 + 0], qv.x, r);
      s[u4 * 4 + 1] = fmaf(a, s[u4 * 4 + 1], wv * kv.y); r = fmaf(s[u4 * 4 + 1], qv.y, r);
      s[u4 * 4 + 2] = fmaf(a, s[u4 * 4 + 2], wv * kv.z); r = fmaf(s[u4 * 4 + 2], qv.z, r);
      s[u4 * 4 + 3] = fmaf(a, s[u4 * 4 + 3], wv * kv.w); r = fmaf(s[u4 * 4 + 3], qv.w, r);
    }
    r += __shfl_xor(r, 1);
    r += __shfl_xor(r, 2);
    if ((tid & 3) == 0)
      RP[((size_t)(b * 1024 + t0 + t) * 8 + h) * 64 + i] = r;
  }

  float* Sf = SF + ((size_t)bh * 16 + chunk) * 4096 + i * 64 + j0;
#pragma unroll
  for (int u4 = 0; u4 < 4; ++u4) {
    float4 v;
    v.x = s[u4 * 4 + 0]; v.y = s[u4 * 4 + 1]; v.z = s[u4 * 4 + 2]; v.w = s[u4 * 4 + 3];
    *(float4*)&Sf[u4 * 4] = v;
  }
}

// Scan phase 2: sequential cross-chunk combine. grid = 16 (b,h). Emits next_mem.
__global__ void scan_phase2(const float* __restrict__ SF, const float* __restrict__ LC,
                            float* __restrict__ SI, float* __restrict__ next_mem) {
  int bh = blockIdx.x;
  int tid = threadIdx.x;  // 256
  float s[16];
#pragma unroll
  for (int z = 0; z < 16; ++z) s[z] = 0.f;
  for (int c = 0; c < 16; ++c) {
#pragma unroll
    for (int z = 0; z < 16; ++z)
      SI[((size_t)bh * 16 + c) * 4096 + z * 256 + tid] = s[z];
    float Lend = LC[(size_t)bh * 1024 + c * 64 + 63];
    float Lpre = c ? LC[(size_t)bh * 1024 + c * 64 - 1] : 0.f;
    float P = expf(Lend - Lpre);
#pragma unroll
    for (int z = 0; z < 16; ++z)
      s[z] = fmaf(P, s[z], SF[((size_t)bh * 16 + c) * 4096 + z * 256 + tid]);
  }
#pragma unroll
  for (int z = 0; z < 16; ++z)
    next_mem[(size_t)bh * 4096 + z * 256 + tid] = s[z];
}

// Scan phase 3: add inter-chunk contribution p_t*(Sinit @ q_t); write bf16 readout.
__global__ __launch_bounds__(256, 2) void scan_phase3(
    const u16* __restrict__ QB, const float* __restrict__ SI, const float* __restrict__ LC,
    const float* __restrict__ RP, u16* __restrict__ AB) {
  int chunk = blockIdx.x, h = blockIdx.y, b = blockIdx.z;
  int bh = b * 8 + h;
  int t0 = chunk * 64;
  __shared__ __align__(16) float sq[4096];
  __shared__ float sL[64];
  int tid = threadIdx.x, lane = tid & 63, wave = tid >> 6;

  const u16* gq = QB + ((size_t)bh * 1024 + t0) * 64;
#pragma unroll
  for (int r = 0; r < 4; ++r) {
    int f = ((wave * 4 + r) * 64 + lane) * 4;
    *(float4*)&sq[f] = b4_to_f4(*(const uint2*)(gq + f));
  }
  if (tid < 64) sL[tid] = LC[(size_t)bh * 1024 + t0 + tid];
  __syncthreads();

  float Lpre = chunk ? LC[(size_t)bh * 1024 + t0 - 1] : 0.f;
  int i = tid >> 2, j0 = (tid & 3) * 16;
  const float* Si = SI + ((size_t)bh * 16 + chunk) * 4096 + i * 64 + j0;
  float S[16];
#pragma unroll
  for (int u4 = 0; u4 < 4; ++u4) {
    float4 v = *(const float4*)&Si[u4 * 4];
    S[u4 * 4 + 0] = v.x; S[u4 * 4 + 1] = v.y; S[u4 * 4 + 2] = v.z; S[u4 * 4 + 3] = v.w;
  }

  for (int t = 0; t < 64; ++t) {
    float p = expf(sL[t] - Lpre);
    float r = 0.f;
#pragma unroll
    for (int u4 = 0; u4 < 4; ++u4) {
      float4 qv = *(const float4*)&sq[t * 64 + j0 + u4 * 4];
      r = fmaf(S[u4 * 4 + 0], qv.x, r);
      r = fmaf(S[u4 * 4 + 1], qv.y, r);
      r = fmaf(S[u4 * 4 + 2], qv.z, r);
      r = fmaf(S[u4 * 4 + 3], qv.w, r);
    }
    r += __shfl_xor(r, 1);
    r += __shfl_xor(r, 2);
    if ((tid & 3) == 0) {
      size_t gi = ((size_t)(b * 1024 + t0 + t) * 8 + h) * 64 + i;
      AB[gi] = f2b(RP[gi] + p * r);
    }
  }
}

// ---------------------------------------------------------------------------
extern "C" void kernel_launch(void* const* d_in, const int* in_sizes, int n_in,
                              void* d_out, int out_size, void* d_ws, size_t ws_size,
                              hipStream_t stream) {
  const float* x = (const float*)d_in[0];
  const float* bmin = (const float*)d_in[1];
  const float* bmax = (const float*)d_in[2];
  const float* motif = (const float*)d_in[3];
  const float* Wk = (const float*)d_in[4];
  const float* bk = (const float*)d_in[5];
  const float* Wq = (const float*)d_in[6];
  const float* bq = (const float*)d_in[7];
  const float* Wv = (const float*)d_in[8];
  const float* bv = (const float*)d_in[9];
  const float* Wo = (const float*)d_in[10];
  const float* bo = (const float*)d_in[11];
  const float* Wd = (const float*)d_in[12];
  const float* bd = (const float*)d_in[13];
  const float* Wgw = (const float*)d_in[14];
  const float* bgw = (const float*)d_in[15];
  const float* Wgf = (const float*)d_in[16];
  const float* bgf = (const float*)d_in[17];
  const float* Wps = (const float*)d_in[18];
  const float* bps = (const float*)d_in[19];
  const float* ln1g = (const float*)d_in[20];
  const float* ln1b = (const float*)d_in[21];
  const float* ln2g = (const float*)d_in[22];
  const float* ln2b = (const float*)d_in[23];
  const float* W1 = (const float*)d_in[24];
  const float* b1 = (const float*)d_in[25];
  const float* W2 = (const float*)d_in[26];
  const float* b2 = (const float*)d_in[27];

  char* ws = (char*)d_ws;
  // persistent: bf16 weights + f32 fused bias
  u16* WTQ = (u16*)(ws + 0);             // 1664x512
  u16* WTO = (u16*)(ws + 1703936);       // 512x512
  u16* WT1 = (u16*)(ws + 2228224);       // 2048x512
  u16* WT2 = (u16*)(ws + 4325376);       // 512x2048
  u16* WTPS = (u16*)(ws + 6422528);      // 512x512
  float* BQV = (float*)(ws + 6946816);   // 1664 f32
  // arena
  u16* XN = (u16*)(ws + 6953984);        // -> 9051136
  float* C0 = (float*)(ws + 9051136);    // 2048x1664 f32 -> 22682624
  u16* KB = (u16*)(ws + 25828352);       // -> 27925504
  u16* QB = (u16*)(ws + 27925504);       // -> 30022656
  u16* VG = (u16*)(ws + 30022656);       // -> 32119808
  float* DEC = (float*)(ws + 32119808);  // -> 32185344
  float* LC = (float*)(ws + 32185344);   // -> 32250880
  float* WW = (float*)(ws + 32250880);   // -> 32316416
  float* RP = (float*)(ws + 32316416);   // -> 36510720
  float* SF = (float*)(ws + 36510720);   // -> 40705024
  float* SI = (float*)(ws + 40705024);   // -> 44899328
  // post-scan aliases (C0/KB.. regions reused once dead)
  u16* AB = (u16*)(ws + 9051136);        // readout bf16 (C0 dead) -> 11148288
  float* X2 = (float*)(ws + 11148288);   // residual f32 -> 15342592
  u16* HB = (u16*)(ws + 15342592);       // ln2 out bf16 -> 17439744
  u16* MID = (u16*)(ws + 17439744);      // 2048x2048 bf16 -> 25828352
  u16* X3B = (u16*)(ws + 25828352);      // x3 bf16 (KB dead) -> 27925504

  float* out0 = (float*)d_out;
  float* out1 = out0 + 1048576;
  float* out2 = out0 + 1114112;
  float* out3 = out0 + 2162688;

  prep_weights<<<3392, 256, 0, stream>>>(Wk, Wq, Wv, Wo, Wps, W1, W2, Wd, Wgw, Wgf,
                                         bk, bq, bv, bd, bgw, bgf,
                                         WTQ, WTO, WTPS, WT1, WT2, BQV);
  ln_f32<<<2048, 256, 0, stream>>>(x, ln1g, ln1b, XN);
  gemm_epi<0><<<dim3(13, 16), 256, 0, stream>>>(XN, WTQ, BQV, C0, nullptr, nullptr,
                                                nullptr, nullptr, 2048, 1664, 512);
  post_qkvg<<<2048, 512, 0, stream>>>(C0, KB, QB, VG, DEC);
  logcum<<<16, 64, 0, stream>>>(DEC, LC, WW);
  scan_phase1<<<dim3(16, 8, 2), 256, 0, stream>>>(KB, QB, VG, DEC, WW, RP, SF);
  scan_phase2<<<16, 256, 0, stream>>>(SF, LC, SI, out1);
  scan_phase3<<<dim3(16, 8, 2), 256, 0, stream>>>(QB, SI, LC, RP, AB);

  gemm_epi<1><<<dim3(4, 16), 256, 0, stream>>>(AB, WTO, bo, X2, nullptr, nullptr,
                                               x, motif, 2048, 512, 512);
  ln_f32<<<2048, 256, 0, stream>>>(X2, ln2g, ln2b, HB);
  gemm_epi<2><<<dim3(16, 16), 256, 0, stream>>>(HB, WT1, b1, nullptr, nullptr, MID,
                                                nullptr, nullptr, 2048, 2048, 512);
  gemm_epi<3><<<dim3(4, 16), 256, 0, stream>>>(MID, WT2, b2, out0, nullptr, X3B,
                                               X2, nullptr, 2048, 512, 2048);
  gemm_epi<4><<<dim3(4, 16), 256, 0, stream>>>(X3B, WTPS, bps, out2, out3, nullptr,
                                               bmin, bmax, 2048, 512, 512);
}

// Round 4
// 285.823 us; speedup vs baseline: 1.1634x; 1.1180x over previous
//
#include <hip/hip_runtime.h>

// HoloGraphBlockV7 — round 4: latency-tolerant GEMM.
// K-loop: double-buffered LDS, raw s_barrier + fine s_waitcnt vmcnt(N) so the
// next tile's global_load_lds stays in flight across the barrier (the compiler
// drains vmcnt(0) at __syncthreads, which killed prefetch at 1 block/CU).
// XOR-swizzled LDS k-blocks kill the 8-way ds_read_b128 bank conflict.
// 64x64-tile config fills the machine for the N=512 GEMMs.

typedef unsigned short u16;
typedef unsigned int u32;
typedef __attribute__((ext_vector_type(8))) short short8;
typedef __attribute__((ext_vector_type(4))) float floatx4;

__device__ __forceinline__ float b2f(u16 u) {
  u32 x = ((u32)u) << 16;
  return __uint_as_float(x);
}
__device__ __forceinline__ u16 f2b(float f) {
  u32 x = __float_as_uint(f);
  u32 r = (x + 0x7fffu + ((x >> 16) & 1u)) >> 16;
  return (u16)r;
}
__device__ __forceinline__ float4 b4_to_f4(uint2 u) {
  float4 r;
  r.x = __uint_as_float((u.x & 0xffffu) << 16);
  r.y = __uint_as_float(u.x & 0xffff0000u);
  r.z = __uint_as_float((u.y & 0xffffu) << 16);
  r.w = __uint_as_float(u.y & 0xffff0000u);
  return r;
}

__device__ __forceinline__ void stage16(const u16* g, u16* lds_wave_base) {
  __builtin_amdgcn_global_load_lds((const __attribute__((address_space(1))) void*)g,
                                   (__attribute__((address_space(3))) void*)lds_wave_base,
                                   16, 0, 0);
}

// Stage a ROWSx32 bf16 tile (k-block kb) into LDS, row-major [row][32] with the
// k-quad XOR swizzle: LDS(row, c) holds global k-block c ^ ((row>>1)&3).
template <int ROWS>
__device__ __forceinline__ void stage_tile(const u16* __restrict__ G, int ldK, int kb,
                                           u16* lds, int tid) {
#pragma unroll
  for (int r = 0; r < ROWS / 64; ++r) {
    int slot = r * 256 + tid;
    int row = slot >> 2;
    int kwg = (slot & 3) ^ ((row >> 1) & 3);
    stage16(G + (size_t)row * ldK + kb * 32 + kwg * 8,
            lds + (size_t)(r * 256 + (tid >> 6) * 64) * 8);
  }
}

// ---------------------------------------------------------------------------
// All weight prep in one kernel (transposes f32->bf16 + gate pack + bias pack).
__global__ __launch_bounds__(256) void prep_weights(
    const float* __restrict__ Wk, const float* __restrict__ Wq,
    const float* __restrict__ Wv, const float* __restrict__ Wo,
    const float* __restrict__ Wps, const float* __restrict__ W1,
    const float* __restrict__ W2, const float* __restrict__ Wd,
    const float* __restrict__ Wgw, const float* __restrict__ Wgf,
    const float* __restrict__ bk, const float* __restrict__ bq,
    const float* __restrict__ bv, const float* __restrict__ bd,
    const float* __restrict__ bgw, const float* __restrict__ bgf,
    u16* __restrict__ WTQ, u16* __restrict__ WTO, u16* __restrict__ WTPS,
    u16* __restrict__ WT1, u16* __restrict__ WT2, float* __restrict__ BQV) {
  int bid = blockIdx.x, tid = threadIdx.x;
  if (bid < 3328) {
    const float* src;
    u16* dst;
    int C, rel, tiles_x;
    if (bid < 256)       { src = Wk;  dst = WTQ;           C = 512;  rel = bid;        tiles_x = 16; }
    else if (bid < 512)  { src = Wq;  dst = WTQ + 262144;  C = 512;  rel = bid - 256;  tiles_x = 16; }
    else if (bid < 768)  { src = Wv;  dst = WTQ + 524288;  C = 512;  rel = bid - 512;  tiles_x = 16; }
    else if (bid < 1024) { src = Wo;  dst = WTO;           C = 512;  rel = bid - 768;  tiles_x = 16; }
    else if (bid < 1280) { src = Wps; dst = WTPS;          C = 512;  rel = bid - 1024; tiles_x = 16; }
    else if (bid < 2304) { src = W1;  dst = WT1;           C = 2048; rel = bid - 1280; tiles_x = 64; }
    else                 { src = W2;  dst = WT2;           C = 512;  rel = bid - 2304; tiles_x = 16; }
    int R = (bid >= 1280 && bid < 2304) ? 512 : (bid >= 2304 ? 2048 : 512);
    int c0 = (rel % tiles_x) * 32, r0 = (rel / tiles_x) * 32;
    __shared__ float tile[32][33];
    int tx = tid & 31, ty = tid >> 5;
#pragma unroll
    for (int i = 0; i < 4; ++i)
      tile[ty + i * 8][tx] = src[(size_t)(r0 + ty + i * 8) * C + c0 + tx];
    __syncthreads();
#pragma unroll
    for (int i = 0; i < 4; ++i)
      dst[(size_t)(c0 + ty + i * 8) * R + r0 + tx] = f2b(tile[tx][ty + i * 8]);
  } else {
    int idx = (bid - 3328) * 256 + tid;
    const int stride = 64 * 256;
    for (int i = idx; i < 128 * 512; i += stride) {
      int local = i >> 9, k = i & 511;
      float v = 0.f;
      if (local < 8) v = Wd[k * 8 + local];
      else if (local < 16) v = Wgw[k * 8 + (local - 8)];
      else if (local < 24) v = Wgf[k * 8 + (local - 16)];
      WTQ[(size_t)(1536 + local) * 512 + k] = f2b(v);
    }
    for (int i = idx; i < 1664; i += stride) {
      float v = 0.f;
      if (i < 512) v = bk[i];
      else if (i < 1024) v = bq[i - 512];
      else if (i < 1536) v = bv[i - 1024];
      else if (i < 1544) v = bd[i - 1536];
      else if (i < 1552) v = bgw[i - 1544];
      else if (i < 1560) v = bgf[i - 1552];
      BQV[i] = v;
    }
  }
}

// ---------------------------------------------------------------------------
// LayerNorm over E=512, f32 in -> bf16 out.
__global__ void ln_f32(const float* __restrict__ X, const float* __restrict__ g,
                       const float* __restrict__ bt, u16* __restrict__ Y) {
  int row = blockIdx.x, tid = threadIdx.x;
  const float* xr = X + (size_t)row * 512;
  float x0 = xr[tid], x1 = xr[tid + 256];
  float s = x0 + x1, ss = x0 * x0 + x1 * x1;
#pragma unroll
  for (int o = 32; o > 0; o >>= 1) { s += __shfl_xor(s, o); ss += __shfl_xor(ss, o); }
  __shared__ float red[8];
  if ((tid & 63) == 0) { red[tid >> 6] = s; red[4 + (tid >> 6)] = ss; }
  __syncthreads();
  float ts = red[0] + red[1] + red[2] + red[3];
  float tss = red[4] + red[5] + red[6] + red[7];
  float mu = ts * (1.f / 512.f);
  float var = tss * (1.f / 512.f) - mu * mu;
  float rstd = 1.0f / sqrtf(var + 1e-5f);
  Y[(size_t)row * 512 + tid] = f2b((x0 - mu) * rstd * g[tid] + bt[tid]);
  Y[(size_t)row * 512 + tid + 256] =
      f2b((x1 - mu) * rstd * g[tid + 256] + bt[tid + 256]);
}

// ---------------------------------------------------------------------------
// Double-buffered bf16 MFMA GEMM with fused epilogues.
// BMxBN tile, BK=32, 256 threads as 2x2 waves; each wave (BM/2)x(BN/2).
// EPI 0: outf = acc+bias
// EPI 1: outf = aux0 + (acc+bias) + 0.1*aux1           (x2 residual)
// EPI 2: outb = bf16(gelu(acc+bias))                   (FFN1 -> MID)
// EPI 3: w = aux0 + acc+bias; outf = w; outb = bf16(w) (FFN2 -> x3)
// EPI 4: p = acc+bias; outf = aux0+p; outf2 = aux1+p   (probe -> out2/out3)
template <int BM, int BN, int EPI>
__global__ __launch_bounds__(256, 2) void gemm_dbuf(
    const u16* __restrict__ A, const u16* __restrict__ BT, const float* __restrict__ bias,
    float* __restrict__ outf, float* __restrict__ outf2, u16* __restrict__ outb,
    const float* __restrict__ aux0, const float* __restrict__ aux1, int M, int N, int K) {
  constexpr int MT = BM / 32;            // mfma m-tiles per wave
  constexpr int NT = BN / 32;            // mfma n-tiles per wave
  constexpr int S = BM / 64 + BN / 64;   // stage insts per thread per tile
  __shared__ __align__(16) u16 As[2][BM * 32];
  __shared__ __align__(16) u16 Bs[2][BN * 32];
  const int tid = threadIdx.x;
  const int lane = tid & 63, wave = tid >> 6;
  const int wm = wave >> 1, wn = wave & 1;
  const int m0 = blockIdx.y * BM, n0 = blockIdx.x * BN;

  floatx4 acc[MT][NT] = {};
  const int fr = lane & 15, kq = lane >> 4;
  const int nk = K >> 5;

  stage_tile<BM>(A + (size_t)m0 * K, K, 0, As[0], tid);
  stage_tile<BN>(BT + (size_t)n0 * K, K, 0, Bs[0], tid);

  for (int kb = 0; kb < nk; ++kb) {
    const int cur = kb & 1;
    if (kb + 1 < nk) {
      stage_tile<BM>(A + (size_t)m0 * K, K, kb + 1, As[cur ^ 1], tid);
      stage_tile<BN>(BT + (size_t)n0 * K, K, kb + 1, Bs[cur ^ 1], tid);
      // wait for CURRENT tile only; leave the S next-tile loads in flight
      if constexpr (S == 4) asm volatile("s_waitcnt vmcnt(4)" ::: "memory");
      else asm volatile("s_waitcnt vmcnt(2)" ::: "memory");
    } else {
      asm volatile("s_waitcnt vmcnt(0)" ::: "memory");
    }
    asm volatile("s_barrier" ::: "memory");

    short8 af[MT], bf[NT];
#pragma unroll
    for (int mt = 0; mt < MT; ++mt) {
      int row = wm * (BM / 2) + mt * 16 + fr;
      af[mt] = *(const short8*)&As[cur][row * 32 + (kq ^ ((row >> 1) & 3)) * 8];
    }
#pragma unroll
    for (int nt = 0; nt < NT; ++nt) {
      int row = wn * (BN / 2) + nt * 16 + fr;
      bf[nt] = *(const short8*)&Bs[cur][row * 32 + (kq ^ ((row >> 1) & 3)) * 8];
    }
#pragma unroll
    for (int mt = 0; mt < MT; ++mt)
#pragma unroll
      for (int nt = 0; nt < NT; ++nt)
        acc[mt][nt] =
            __builtin_amdgcn_mfma_f32_16x16x32_bf16(af[mt], bf[nt], acc[mt][nt], 0, 0, 0);
    asm volatile("s_waitcnt lgkmcnt(0)" ::: "memory");
    asm volatile("s_barrier" ::: "memory");
  }

  const int col = lane & 15;
  const int rbase = (lane >> 4) * 4;
#pragma unroll
  for (int nt = 0; nt < NT; ++nt) {
    int gc = n0 + wn * (BN / 2) + nt * 16 + col;
    float bvv = bias[gc];
#pragma unroll
    for (int mt = 0; mt < MT; ++mt) {
      int gr = m0 + wm * (BM / 2) + mt * 16 + rbase;
#pragma unroll
      for (int r = 0; r < 4; ++r) {
        size_t idx = (size_t)(gr + r) * N + gc;
        float v = acc[mt][nt][r] + bvv;
        if constexpr (EPI == 0) {
          outf[idx] = v;
        } else if constexpr (EPI == 1) {
          outf[idx] = aux0[idx] + v + 0.1f * aux1[idx];
        } else if constexpr (EPI == 2) {
          outb[idx] = f2b(0.5f * v * (1.f + erff(v * 0.70710678118654752f)));
        } else if constexpr (EPI == 3) {
          float w = aux0[idx] + v;
          outf[idx] = w;
          outb[idx] = f2b(w);
        } else {
          outf[idx] = aux0[idx] + v;
          outf2[idx] = aux1[idx] + v;
        }
      }
    }
  }
}

// ---------------------------------------------------------------------------
// Per-token epilogue of the QKV+gates GEMM.
__global__ __launch_bounds__(512) void post_qkvg(const float* __restrict__ C0,
                                                 u16* __restrict__ KB, u16* __restrict__ QB,
                                                 u16* __restrict__ VG,
                                                 float* __restrict__ DEC) {
  int tok = blockIdx.x;
  int b = tok >> 10, t = tok & 1023;
  int tid = threadIdx.x;
  int h = tid >> 6, d = tid & 63;
  const float* row = C0 + (size_t)tok * 1664;

  float dl = row[1536 + h], gwl = row[1544 + h], gfl = row[1552 + h];
  float dd = dl > 20.f ? dl : log1pf(expf(dl));
  float sw = 1.f / (1.f + expf(-gwl));
  float gw = sw * sw;
  float sf = 1.f / (1.f + expf(-gfl));
  float gf = 1.f - sf * sf;

  size_t obase = ((size_t)(b * 8 + h) * 1024 + t) * 64 + d;

  float kx = row[h * 64 + d];
  float ssk = kx * kx;
#pragma unroll
  for (int o = 32; o > 0; o >>= 1) ssk += __shfl_xor(ssk, o);
  KB[obase] = f2b(kx / fmaxf(sqrtf(ssk), 1e-12f));

  float qx = row[512 + h * 64 + d];
  float ssq = qx * qx;
#pragma unroll
  for (int o = 32; o > 0; o >>= 1) ssq += __shfl_xor(ssq, o);
  QB[obase] = f2b(qx / fmaxf(sqrtf(ssq), 1e-12f));

  float vx = tanhf(row[1024 + h * 64 + d]);
  VG[obase] = f2b(vx * (dd * gw));

  if (d == 0)
    DEC[(size_t)(b * 8 + h) * 1024 + t] = fminf(fmaxf(dd * gf, 1e-6f), 0.999f);
}

// Cumulative log-decay per (b,h); update weight w_t = c/(c+1e-8), c = exp(Lcum).
__global__ void logcum(const float* __restrict__ DEC, float* __restrict__ LC,
                       float* __restrict__ WW) {
  int bh = blockIdx.x;
  int lane = threadIdx.x;  // 64
  size_t base = (size_t)bh * 1024 + lane * 16;
  float loc[16];
  float run = 0.f;
#pragma unroll
  for (int i = 0; i < 16; ++i) { run += logf(DEC[base + i]); loc[i] = run; }
  float x = run;
#pragma unroll
  for (int o = 1; o < 64; o <<= 1) {
    float v = __shfl_up(x, o);
    if (lane >= o) x += v;
  }
  float excl = x - run;
#pragma unroll
  for (int i = 0; i < 16; ++i) {
    float L = excl + loc[i];
    LC[base + i] = L;
    float c = expf(L);
    WW[base + i] = c / (c + 1e-8f);
  }
}

// ---------------------------------------------------------------------------
// Scan phase 1: per (chunk,h,b) local scan of 64 steps with zero init.
__global__ __launch_bounds__(256, 2) void scan_phase1(
    const u16* __restrict__ KB, const u16* __restrict__ QB, const u16* __restrict__ VG,
    const float* __restrict__ DEC, const float* __restrict__ WW,
    float* __restrict__ RP, float* __restrict__ SF) {
  int chunk = blockIdx.x, h = blockIdx.y, b = blockIdx.z;
  int bh = b * 8 + h;
  int t0 = chunk * 64;
  __shared__ __align__(16) float sk[4096], sq[4096], sv[4096];
  __shared__ float lsa[64], lsw[64];
  int tid = threadIdx.x, lane = tid & 63, wave = tid >> 6;

  const u16* gk = KB + ((size_t)bh * 1024 + t0) * 64;
  const u16* gq = QB + ((size_t)bh * 1024 + t0) * 64;
  const u16* gv = VG + ((size_t)bh * 1024 + t0) * 64;
#pragma unroll
  for (int r = 0; r < 4; ++r) {
    int f = ((wave * 4 + r) * 64 + lane) * 4;
    *(float4*)&sk[f] = b4_to_f4(*(const uint2*)(gk + f));
    *(float4*)&sq[f] = b4_to_f4(*(const uint2*)(gq + f));
    *(float4*)&sv[f] = b4_to_f4(*(const uint2*)(gv + f));
  }
  if (tid < 64) {
    lsa[tid] = DEC[(size_t)bh * 1024 + t0 + tid];
    lsw[tid] = WW[(size_t)bh * 1024 + t0 + tid];
  }
  __syncthreads();

  int i = tid >> 2, j0 = (tid & 3) * 16;
  float s[16];
#pragma unroll
  for (int z = 0; z < 16; ++z) s[z] = 0.f;

  for (int t = 0; t < 64; ++t) {
    float a = lsa[t], w = lsw[t];
    float wv = w * sv[t * 64 + i];
    float r = 0.f;
#pragma unroll
    for (int u4 = 0; u4 < 4; ++u4) {
      float4 kv = *(const float4*)&sk[t * 64 + j0 + u4 * 4];
      float4 qv = *(const float4*)&sq[t * 64 + j0 + u4 * 4];
      s[u4 * 4 + 0] = fmaf(a, s[u4 * 4 + 0], wv * kv.x); r = fmaf(s[u4 * 4 + 0], qv.x, r);
      s[u4 * 4 + 1] = fmaf(a, s[u4 * 4 + 1], wv * kv.y); r = fmaf(s[u4 * 4 + 1], qv.y, r);
      s[u4 * 4 + 2] = fmaf(a, s[u4 * 4 + 2], wv * kv.z); r = fmaf(s[u4 * 4 + 2], qv.z, r);
      s[u4 * 4 + 3] = fmaf(a, s[u4 * 4 + 3], wv * kv.w); r = fmaf(s[u4 * 4 + 3], qv.w, r);
    }
    r += __shfl_xor(r, 1);
    r += __shfl_xor(r, 2);
    if ((tid & 3) == 0)
      RP[((size_t)(b * 1024 + t0 + t) * 8 + h) * 64 + i] = r;
  }

  float* Sf = SF + ((size_t)bh * 16 + chunk) * 4096 + i * 64 + j0;
#pragma unroll
  for (int u4 = 0; u4 < 4; ++u4) {
    float4 v;
    v.x = s[u4 * 4 + 0]; v.y = s[u4 * 4 + 1]; v.z = s[u4 * 4 + 2]; v.w = s[u4 * 4 + 3];
    *(float4*)&Sf[u4 * 4] = v;
  }
}

// Scan phase 2: sequential cross-chunk combine. grid = 16 (b,h). Emits next_mem.
__global__ void scan_phase2(const float* __restrict__ SF, const float* __restrict__ LC,
                            float* __restrict__ SI, float* __restrict__ next_mem) {
  int bh = blockIdx.x;
  int tid = threadIdx.x;  // 256
  float s[16];
#pragma unroll
  for (int z = 0; z < 16; ++z) s[z] = 0.f;
  for (int c = 0; c < 16; ++c) {
#pragma unroll
    for (int z = 0; z < 16; ++z)
      SI[((size_t)bh * 16 + c) * 4096 + z * 256 + tid] = s[z];
    float Lend = LC[(size_t)bh * 1024 + c * 64 + 63];
    float Lpre = c ? LC[(size_t)bh * 1024 + c * 64 - 1] : 0.f;
    float P = expf(Lend - Lpre);
#pragma unroll
    for (int z = 0; z < 16; ++z)
      s[z] = fmaf(P, s[z], SF[((size_t)bh * 16 + c) * 4096 + z * 256 + tid]);
  }
#pragma unroll
  for (int z = 0; z < 16; ++z)
    next_mem[(size_t)bh * 4096 + z * 256 + tid] = s[z];
}

// Scan phase 3: add inter-chunk contribution p_t*(Sinit @ q_t); write bf16 readout.
__global__ __launch_bounds__(256, 2) void scan_phase3(
    const u16* __restrict__ QB, const float* __restrict__ SI, const float* __restrict__ LC,
    const float* __restrict__ RP, u16* __restrict__ AB) {
  int chunk = blockIdx.x, h = blockIdx.y, b = blockIdx.z;
  int bh = b * 8 + h;
  int t0 = chunk * 64;
  __shared__ __align__(16) float sq[4096];
  __shared__ float sL[64];
  int tid = threadIdx.x, lane = tid & 63, wave = tid >> 6;

  const u16* gq = QB + ((size_t)bh * 1024 + t0) * 64;
#pragma unroll
  for (int r = 0; r < 4; ++r) {
    int f = ((wave * 4 + r) * 64 + lane) * 4;
    *(float4*)&sq[f] = b4_to_f4(*(const uint2*)(gq + f));
  }
  if (tid < 64) sL[tid] = LC[(size_t)bh * 1024 + t0 + tid];
  __syncthreads();

  float Lpre = chunk ? LC[(size_t)bh * 1024 + t0 - 1] : 0.f;
  int i = tid >> 2, j0 = (tid & 3) * 16;
  const float* Si = SI + ((size_t)bh * 16 + chunk) * 4096 + i * 64 + j0;
  float S[16];
#pragma unroll
  for (int u4 = 0; u4 < 4; ++u4) {
    float4 v = *(const float4*)&Si[u4 * 4];
    S[u4 * 4 + 0] = v.x; S[u4 * 4 + 1] = v.y; S[u4 * 4 + 2] = v.z; S[u4 * 4 + 3] = v.w;
  }

  for (int t = 0; t < 64; ++t) {
    float p = expf(sL[t] - Lpre);
    float r = 0.f;
#pragma unroll
    for (int u4 = 0; u4 < 4; ++u4) {
      float4 qv = *(const float4*)&sq[t * 64 + j0 + u4 * 4];
      r = fmaf(S[u4 * 4 + 0], qv.x, r);
      r = fmaf(S[u4 * 4 + 1], qv.y, r);
      r = fmaf(S[u4 * 4 + 2], qv.z, r);
      r = fmaf(S[u4 * 4 + 3], qv.w, r);
    }
    r += __shfl_xor(r, 1);
    r += __shfl_xor(r, 2);
    if ((tid & 3) == 0) {
      size_t gi = ((size_t)(b * 1024 + t0 + t) * 8 + h) * 64 + i;
      AB[gi] = f2b(RP[gi] + p * r);
    }
  }
}

// ---------------------------------------------------------------------------
extern "C" void kernel_launch(void* const* d_in, const int* in_sizes, int n_in,
                              void* d_out, int out_size, void* d_ws, size_t ws_size,
                              hipStream_t stream) {
  const float* x = (const float*)d_in[0];
  const float* bmin = (const float*)d_in[1];
  const float* bmax = (const float*)d_in[2];
  const float* motif = (const float*)d_in[3];
  const float* Wk = (const float*)d_in[4];
  const float* bk = (const float*)d_in[5];
  const float* Wq = (const float*)d_in[6];
  const float* bq = (const float*)d_in[7];
  const float* Wv = (const float*)d_in[8];
  const float* bv = (const float*)d_in[9];
  const float* Wo = (const float*)d_in[10];
  const float* bo = (const float*)d_in[11];
  const float* Wd = (const float*)d_in[12];
  const float* bd = (const float*)d_in[13];
  const float* Wgw = (const float*)d_in[14];
  const float* bgw = (const float*)d_in[15];
  const float* Wgf = (const float*)d_in[16];
  const float* bgf = (const float*)d_in[17];
  const float* Wps = (const float*)d_in[18];
  const float* bps = (const float*)d_in[19];
  const float* ln1g = (const float*)d_in[20];
  const float* ln1b = (const float*)d_in[21];
  const float* ln2g = (const float*)d_in[22];
  const float* ln2b = (const float*)d_in[23];
  const float* W1 = (const float*)d_in[24];
  const float* b1 = (const float*)d_in[25];
  const float* W2 = (const float*)d_in[26];
  const float* b2 = (const float*)d_in[27];

  char* ws = (char*)d_ws;
  // persistent: bf16 weights + f32 fused bias
  u16* WTQ = (u16*)(ws + 0);             // 1664x512
  u16* WTO = (u16*)(ws + 1703936);       // 512x512
  u16* WT1 = (u16*)(ws + 2228224);       // 2048x512
  u16* WT2 = (u16*)(ws + 4325376);       // 512x2048
  u16* WTPS = (u16*)(ws + 6422528);      // 512x512
  float* BQV = (float*)(ws + 6946816);   // 1664 f32
  // arena
  u16* XN = (u16*)(ws + 6953984);        // -> 9051136
  float* C0 = (float*)(ws + 9051136);    // 2048x1664 f32 -> 22682624
  u16* KB = (u16*)(ws + 25828352);       // -> 27925504
  u16* QB = (u16*)(ws + 27925504);       // -> 30022656
  u16* VG = (u16*)(ws + 30022656);       // -> 32119808
  float* DEC = (float*)(ws + 32119808);  // -> 32185344
  float* LC = (float*)(ws + 32185344);   // -> 32250880
  float* WW = (float*)(ws + 32250880);   // -> 32316416
  float* RP = (float*)(ws + 32316416);   // -> 36510720
  float* SF = (float*)(ws + 36510720);   // -> 40705024
  float* SI = (float*)(ws + 40705024);   // -> 44899328
  // post-scan aliases (C0/KB.. regions reused once dead)
  u16* AB = (u16*)(ws + 9051136);        // readout bf16 (C0 dead) -> 11148288
  float* X2 = (float*)(ws + 11148288);   // residual f32 -> 15342592
  u16* HB = (u16*)(ws + 15342592);       // ln2 out bf16 -> 17439744
  u16* MID = (u16*)(ws + 17439744);      // 2048x2048 bf16 -> 25828352
  u16* X3B = (u16*)(ws + 25828352);      // x3 bf16 (KB dead) -> 27925504

  float* out0 = (float*)d_out;
  float* out1 = out0 + 1048576;
  float* out2 = out0 + 1114112;
  float* out3 = out0 + 2162688;

  prep_weights<<<3392, 256, 0, stream>>>(Wk, Wq, Wv, Wo, Wps, W1, W2, Wd, Wgw, Wgf,
                                         bk, bq, bv, bd, bgw, bgf,
                                         WTQ, WTO, WTPS, WT1, WT2, BQV);
  ln_f32<<<2048, 256, 0, stream>>>(x, ln1g, ln1b, XN);
  gemm_dbuf<128, 128, 0><<<dim3(13, 16), 256, 0, stream>>>(
      XN, WTQ, BQV, C0, nullptr, nullptr, nullptr, nullptr, 2048, 1664, 512);
  post_qkvg<<<2048, 512, 0, stream>>>(C0, KB, QB, VG, DEC);
  logcum<<<16, 64, 0, stream>>>(DEC, LC, WW);
  scan_phase1<<<dim3(16, 8, 2), 256, 0, stream>>>(KB, QB, VG, DEC, WW, RP, SF);
  scan_phase2<<<16, 256, 0, stream>>>(SF, LC, SI, out1);
  scan_phase3<<<dim3(16, 8, 2), 256, 0, stream>>>(QB, SI, LC, RP, AB);

  gemm_dbuf<64, 64, 1><<<dim3(8, 32), 256, 0, stream>>>(
      AB, WTO, bo, X2, nullptr, nullptr, x, motif, 2048, 512, 512);
  ln_f32<<<2048, 256, 0, stream>>>(X2, ln2g, ln2b, HB);
  gemm_dbuf<128, 128, 2><<<dim3(16, 16), 256, 0, stream>>>(
      HB, WT1, b1, nullptr, nullptr, MID, nullptr, nullptr, 2048, 2048, 512);
  gemm_dbuf<64, 64, 3><<<dim3(8, 32), 256, 0, stream>>>(
      MID, WT2, b2, out0, nullptr, X3B, X2, nullptr, 2048, 512, 2048);
  gemm_dbuf<64, 64, 4><<<dim3(8, 32), 256, 0, stream>>>(
      X3B, WTPS, bps, out2, out3, nullptr, bmin, bmax, 2048, 512, 512);
}